// Round 1
// baseline (158.456 us; speedup 1.0000x reference)
//
#include <hip/hip_runtime.h>

// SE(3) exp + point transform — pure-register version, no LDS, no barriers.
//
// Previous version staged through LDS to get lane-contiguous float4s; rocprof
// showed it was latency-bound (HBM 30%, VALU 17%, occ 67%): the two
// vmcnt(0)+barrier drains serialized every block into load/compute/store
// phases with only 8 blocks/CU resident.
//
// Here each thread owns 4 consecutive points = 12 consecutive floats =
// 3 consecutive float4s (48 B lane stride). Per wave-instruction the lanes
// touch 48 lines partially, but the 3 loads together cover the 3 KB wave
// span exactly once -> same HBM/L2 traffic, L1 absorbs overlap. No
// synchronization at all: waves stream independently, latency hidden by TLP
// at full 32-wave/CU occupancy.

__device__ __forceinline__ float rfl(float x) {
    // block-uniform value -> SGPR (all lanes hold identical values)
    return __uint_as_float(__builtin_amdgcn_readfirstlane(__float_as_uint(x)));
}

__global__ __launch_bounds__(256) void se3_apply_kernel(
    const float* __restrict__ X,      // (BT, N, 3) flattened
    const float* __restrict__ dofs,   // (BT, 6)
    float* __restrict__ out,
    int n3,                            // floats per (b,t) = N*3
    int tilesPerBT)
{
    const int bt   = blockIdx.x / tilesPerBT;
    const int tile = blockIdx.x - bt * tilesPerBT;
    const int t    = threadIdx.x;

    const int fInBT = tile * 3072 + t * 12;                 // float offset within bt
    const long long baseF = (long long)bt * (long long)n3 + (long long)fInBT;
    const float4* __restrict__ Xp = (const float4*)(X + baseF);
    float4* __restrict__ Op       = (float4*)(out + baseF);

    // ---- issue the 3 independent loads first (overlap with SE3 setup) ----
    const bool full = (fInBT + 12) <= n3;
    float4 v0, v1, v2;
    if (full) { v0 = Xp[0]; v1 = Xp[1]; v2 = Xp[2]; }

    // ---- SE(3) exponential (block-uniform) ----
    const float* d = dofs + bt * 6;
    const float tx = d[0], ty = d[1], tz = d[2];
    const float wx = d[3], wy = d[4], wz = d[5];

    const float nrm2  = wx * wx + wy * wy + wz * wz;
    const float th2   = fmaxf(nrm2, 1e-4f);      // jnp.clip(nrms, 1e-4) (min only)
    const float theta = sqrtf(th2);
    const float st = sinf(theta);
    const float ct = cosf(theta);
    const float f1 = st / theta;
    const float f2 = (1.0f - ct) / th2;
    const float f3 = (theta - st) / (th2 * theta);

    const float xx = wx * wx, yy = wy * wy, zz = wz * wz;
    const float xy = wx * wy, xz = wx * wz, yz = wy * wz;

    // rotation + V*t, hoisted to SGPRs via readfirstlane (uniform by construction)
    const float R00 = rfl(1.0f - f2 * (yy + zz));
    const float R01 = rfl(f2 * xy - f1 * wz);
    const float R02 = rfl(f2 * xz + f1 * wy);
    const float R10 = rfl(f2 * xy + f1 * wz);
    const float R11 = rfl(1.0f - f2 * (xx + zz));
    const float R12 = rfl(f2 * yz - f1 * wx);
    const float R20 = rfl(f2 * xz - f1 * wy);
    const float R21 = rfl(f2 * yz + f1 * wx);
    const float R22 = rfl(1.0f - f2 * (xx + yy));

    const float V00 = 1.0f - f3 * (yy + zz);
    const float V01 = f3 * xy - f2 * wz;
    const float V02 = f3 * xz + f2 * wy;
    const float V10 = f3 * xy + f2 * wz;
    const float V11 = 1.0f - f3 * (xx + zz);
    const float V12 = f3 * yz - f2 * wx;
    const float V20 = f3 * xz - f2 * wy;
    const float V21 = f3 * yz + f2 * wx;
    const float V22 = 1.0f - f3 * (xx + yy);

    const float Tx = rfl(V00 * tx + V01 * ty + V02 * tz);
    const float Ty = rfl(V10 * tx + V11 * ty + V12 * tz);
    const float Tz = rfl(V20 * tx + V21 * ty + V22 * tz);

    if (full) {
        // 4 points unpacked from 3 float4s
        const float x0 = v0.x, y0 = v0.y, z0 = v0.z;
        const float x1 = v0.w, y1 = v1.x, z1 = v1.y;
        const float x2 = v1.z, y2 = v1.w, z2 = v2.x;
        const float x3 = v2.y, y3 = v2.z, z3 = v2.w;

        float4 o0, o1, o2;
        o0.x = fmaf(R00, x0, fmaf(R01, y0, fmaf(R02, z0, Tx)));
        o0.y = fmaf(R10, x0, fmaf(R11, y0, fmaf(R12, z0, Ty)));
        o0.z = fmaf(R20, x0, fmaf(R21, y0, fmaf(R22, z0, Tz)));
        o0.w = fmaf(R00, x1, fmaf(R01, y1, fmaf(R02, z1, Tx)));
        o1.x = fmaf(R10, x1, fmaf(R11, y1, fmaf(R12, z1, Ty)));
        o1.y = fmaf(R20, x1, fmaf(R21, y1, fmaf(R22, z1, Tz)));
        o1.z = fmaf(R00, x2, fmaf(R01, y2, fmaf(R02, z2, Tx)));
        o1.w = fmaf(R10, x2, fmaf(R11, y2, fmaf(R12, z2, Ty)));
        o2.x = fmaf(R20, x2, fmaf(R21, y2, fmaf(R22, z2, Tz)));
        o2.y = fmaf(R00, x3, fmaf(R01, y3, fmaf(R02, z3, Tx)));
        o2.z = fmaf(R10, x3, fmaf(R11, y3, fmaf(R12, z3, Ty)));
        o2.w = fmaf(R20, x3, fmaf(R21, y3, fmaf(R22, z3, Tz)));

        Op[0] = o0; Op[1] = o1; Op[2] = o2;
    } else {
        // generic tail: whole points only (n3 is always a multiple of 3)
        for (int f = fInBT; f + 3 <= n3; f += 3) {
            const long long g = (long long)bt * (long long)n3 + f;
            const float px = X[g + 0], py = X[g + 1], pz = X[g + 2];
            out[g + 0] = fmaf(R00, px, fmaf(R01, py, fmaf(R02, pz, Tx)));
            out[g + 1] = fmaf(R10, px, fmaf(R11, py, fmaf(R12, pz, Ty)));
            out[g + 2] = fmaf(R20, px, fmaf(R21, py, fmaf(R22, pz, Tz)));
        }
    }
}

extern "C" void kernel_launch(void* const* d_in, const int* in_sizes, int n_in,
                              void* d_out, int out_size, void* d_ws, size_t ws_size,
                              hipStream_t stream) {
    const float* X    = (const float*)d_in[0];
    const float* dofs = (const float*)d_in[1];
    float* out        = (float*)d_out;

    const int BT = in_sizes[1] / 6;            // 64*28 = 1792
    const int n3 = in_sizes[0] / BT;           // 4096*3 = 12288 floats per bt

    const int tilesPerBT = (n3 + 3071) / 3072; // 4 for N=4096

    dim3 grid((unsigned)(BT * tilesPerBT));    // 7168 blocks
    se3_apply_kernel<<<grid, 256, 0, stream>>>(X, dofs, out, n3, tilesPerBT);
}